// Round 11
// baseline (225.840 us; speedup 1.0000x reference)
//
#include <hip/hip_runtime.h>
#include <hip/hip_bf16.h>

typedef __bf16 bf16_t;
typedef __attribute__((ext_vector_type(8))) __bf16 bf16x8;
typedef __attribute__((ext_vector_type(4))) __bf16 bf16x4;
typedef __attribute__((ext_vector_type(4))) float f32x4;

// Problem constants
// B=2, N=2048, D=256, H=8, M=2, NN=2048, K=8, dh=32

static __device__ __forceinline__ unsigned pk2(float x, float y) {
    unsigned short ux = __builtin_bit_cast(unsigned short, (bf16_t)x);
    unsigned short uy = __builtin_bit_cast(unsigned short, (bf16_t)y);
    return (unsigned)ux | ((unsigned)uy << 16);
}

// ---------------------------------------------------------------------------
// Kernel 0: convert weights to bf16
// ---------------------------------------------------------------------------
__global__ __launch_bounds__(256) void wconv_kernel(const float* __restrict__ w_in,
                                                    const float* __restrict__ w_out,
                                                    bf16_t* __restrict__ w_in_b,
                                                    bf16_t* __restrict__ w_out_b) {
    int i = blockIdx.x * 256 + threadIdx.x;
    if (i < 768 * 256) w_in_b[i] = (bf16_t)w_in[i];
    if (i < 256 * 256) w_out_b[i] = (bf16_t)w_out[i];
}

// ---------------------------------------------------------------------------
// Kernel 1: KNN top-8, one WAVE per query. (unchanged, proven)
// ---------------------------------------------------------------------------
__global__ __launch_bounds__(1024) void knn_kernel(const float* __restrict__ cur_pts,
                                                   const float* __restrict__ nbr_pts,
                                                   int* __restrict__ idx_out) {
    int p = blockIdx.y;  // 0..5 : 0,1 = current batches; 2..5 = (m*2+b)
    const float* pts = (p < 2) ? (cur_pts + (size_t)p * 2048 * 3)
                               : (nbr_pts + (size_t)(p - 2) * 2048 * 3);

    __shared__ __align__(16) float4 spts[2048];

    int tid = threadIdx.x;
    for (int i = tid; i < 2048; i += 1024) {
        float x = pts[i * 3 + 0], y = pts[i * 3 + 1], z = pts[i * 3 + 2];
        float sq = __fadd_rn(__fadd_rn(__fmul_rn(x, x), __fmul_rn(y, y)), __fmul_rn(z, z));
        spts[i] = make_float4(x, y, z, sq);
    }
    __syncthreads();

    int wave = tid >> 6, lane = tid & 63;
    int q = blockIdx.x * 16 + wave;
    float4 qp4 = spts[q];

    float dist[8];
    int di[8];
#pragma unroll
    for (int r = 0; r < 8; r++) { dist[r] = 3.4e38f; di[r] = 0x7fffffff; }

    for (int t = 0; t < 32; t++) {
        int j = t * 64 + lane;
        float4 pp = spts[j];
        float dot = __fadd_rn(__fadd_rn(__fmul_rn(qp4.x, pp.x), __fmul_rn(qp4.y, pp.y)),
                              __fmul_rn(qp4.z, pp.z));
        float d2 = __fsub_rn(__fadd_rn(qp4.w, pp.w), __fmul_rn(2.0f, dot));
        if (d2 < dist[7]) {
#pragma unroll
            for (int r = 7; r >= 1; --r) {
                bool cm = d2 < dist[r - 1];
                bool cr = d2 < dist[r];
                float nd = cm ? dist[r - 1] : (cr ? d2 : dist[r]);
                int ni = cm ? di[r - 1] : (cr ? j : di[r]);
                dist[r] = nd; di[r] = ni;
            }
            if (d2 < dist[0]) { dist[0] = d2; di[0] = j; }
        }
    }

    int res[8];
#pragma unroll
    for (int r = 0; r < 8; r++) {
        float bd = dist[0];
        int bi = di[0];
#pragma unroll
        for (int m = 1; m < 64; m <<= 1) {
            float od = __shfl_xor(bd, m);
            int oi = __shfl_xor(bi, m);
            if (od < bd || (od == bd && oi < bi)) { bd = od; bi = oi; }
        }
        res[r] = bi;
        bool win = (di[0] == bi);
#pragma unroll
        for (int k = 0; k < 7; k++) {
            dist[k] = win ? dist[k + 1] : dist[k];
            di[k]   = win ? di[k + 1]   : di[k];
        }
        if (win) { dist[7] = 3.4e38f; di[7] = 0x7fffffff; }
    }

    if (lane == 0) {
        int4* o = (int4*)(idx_out + ((size_t)p * 2048 + q) * 8);
        o[0] = make_int4(res[0], res[1], res[2], res[3]);
        o[1] = make_int4(res[4], res[5], res[6], res[7]);
    }
}

// ---------------------------------------------------------------------------
// Kernel 2: gather neighbor features, edge = f - mean(nbr). (unchanged)
// ---------------------------------------------------------------------------
__global__ __launch_bounds__(64) void edge_kernel(const float* __restrict__ cur_feat,
                                                  const float* __restrict__ nbr_feat,
                                                  const int* __restrict__ idx_buf,
                                                  bf16_t* __restrict__ cur_edge,
                                                  bf16_t* __restrict__ all_nbr) {
    int blk = blockIdx.x;
    int p = blk >> 11, q = blk & 2047;
    const float* feat;
    bf16_t* outp;
    if (p < 2) {
        feat = cur_feat + (size_t)p * 2048 * 256;
        outp = cur_edge + ((size_t)p * 2048 + q) * 256;
    } else {
        int mb = p - 2;
        int m = mb >> 1, bb = mb & 1;
        feat = nbr_feat + (size_t)mb * 2048 * 256;
        outp = all_nbr + ((size_t)bb * 4096 + m * 2048 + q) * 256;
    }
    const int* idx = idx_buf + ((size_t)p * 2048 + q) * 8;
    int t = threadIdx.x;
    float4 self = ((const float4*)(feat + (size_t)q * 256))[t];
    float sx = 0.f, sy = 0.f, sz = 0.f, sw = 0.f;
#pragma unroll
    for (int r = 0; r < 8; r++) {
        float4 f = ((const float4*)(feat + (size_t)idx[r] * 256))[t];
        sx += f.x; sy += f.y; sz += f.z; sw += f.w;
    }
    bf16x4 v;
    v[0] = (bf16_t)(self.x - sx * 0.125f);
    v[1] = (bf16_t)(self.y - sy * 0.125f);
    v[2] = (bf16_t)(self.z - sz * 0.125f);
    v[3] = (bf16_t)(self.w - sw * 0.125f);
    *(bf16x4*)(outp + 4 * t) = v;
}

// ---------------------------------------------------------------------------
// Kernel 3: QKV projections via bf16 MFMA. z=0: qp (scaled), z=1: kp,
// z=2: vp ROW-major (coalesced); vt_kernel transposes after.
// ---------------------------------------------------------------------------
__global__ __launch_bounds__(256) void qkv_kernel(const bf16_t* __restrict__ cur_edge,
                                                  const bf16_t* __restrict__ all_nbr,
                                                  const bf16_t* __restrict__ w_in,
                                                  const float* __restrict__ b_in,
                                                  bf16_t* __restrict__ qp,
                                                  bf16_t* __restrict__ kp,
                                                  bf16_t* __restrict__ vp) {
    int z = blockIdx.z;
    int Mrows = (z == 0) ? 4096 : 8192;
    int m0base = blockIdx.y * 64;
    if (m0base >= Mrows) return;
    const bf16_t* A = (z == 0) ? cur_edge : all_nbr;
    const bf16_t* W = w_in + (size_t)z * 256 * 256;

    int wave = threadIdx.x >> 6, lane = threadIdx.x & 63;
    int wr = wave >> 1, wc = wave & 1;
    int m0 = m0base + wr * 32;
    int n0 = blockIdx.x * 64 + wc * 32;
    int lr = lane & 15, lg = lane >> 4;

    f32x4 acc[2][2] = {};
    for (int kc = 0; kc < 256; kc += 32) {
        bf16x8 a[2], b[2];
#pragma unroll
        for (int i = 0; i < 2; i++)
            a[i] = *(const bf16x8*)(A + (size_t)(m0 + i * 16 + lr) * 256 + kc + lg * 8);
#pragma unroll
        for (int i = 0; i < 2; i++)
            b[i] = *(const bf16x8*)(W + (size_t)(n0 + i * 16 + lr) * 256 + kc + lg * 8);
#pragma unroll
        for (int i = 0; i < 2; i++)
#pragma unroll
            for (int j = 0; j < 2; j++)
                acc[i][j] = __builtin_amdgcn_mfma_f32_16x16x32_bf16(a[i], b[j], acc[i][j], 0, 0, 0);
    }

    const float inv_s = 0.17677669529663687f;  // 1/sqrt(32)
#pragma unroll
    for (int i = 0; i < 2; i++)
#pragma unroll
        for (int j = 0; j < 2; j++)
#pragma unroll
            for (int r = 0; r < 4; r++) {
                int mm = m0 + i * 16 + lg * 4 + r;
                int nn = n0 + j * 16 + lr;
                float v = acc[i][j][r] + b_in[z * 256 + nn];
                if (z == 0) {
                    qp[(size_t)mm * 256 + nn] = (bf16_t)(v * inv_s);
                } else if (z == 1) {
                    kp[(size_t)mm * 256 + nn] = (bf16_t)v;
                } else {
                    vp[(size_t)mm * 256 + nn] = (bf16_t)v;
                }
            }
}

// ---------------------------------------------------------------------------
// Kernel 3b: transpose vp -> vpT [b,h,32dd][4096kv] via padded LDS tile.
// ---------------------------------------------------------------------------
__global__ __launch_bounds__(256) void vt_kernel(const bf16_t* __restrict__ vp,
                                                 bf16_t* __restrict__ vpT) {
    int kc = blockIdx.x;          // kv chunk of 64 (0..63)
    int bh = blockIdx.y;          // 0..15
    int b = bh >> 3, h = bh & 7;
    __shared__ bf16_t tile[64][34];
    int tid = threadIdx.x;

    const bf16_t* src = vp + ((size_t)b * 4096 + kc * 64) * 256 + h * 32;
    int dd0 = (tid & 7) * 4, kvr = tid >> 3;          // 32 kv rows per pass
#pragma unroll
    for (int it = 0; it < 2; it++) {
        int kv = it * 32 + kvr;
        bf16x4 v = *(const bf16x4*)(src + (size_t)kv * 256 + dd0);
#pragma unroll
        for (int j = 0; j < 4; j++) tile[kv][dd0 + j] = v[j];
    }
    __syncthreads();

    bf16_t* dst = vpT + (((size_t)b * 8 + h) * 32) * 4096 + kc * 64;
    int kv0 = (tid & 15) * 4, ddr0 = tid >> 4;        // 16 dd rows per pass
#pragma unroll
    for (int it = 0; it < 2; it++) {
        int dd = it * 16 + ddr0;
        bf16x4 v;
#pragma unroll
        for (int j = 0; j < 4; j++) v[j] = tile[kv0 + j][dd];
        *(bf16x4*)(dst + (size_t)dd * 4096 + kv0) = v;
    }
}

// ---------------------------------------------------------------------------
// Kernel 4: cross attention, kv-SPLIT (CSPLIT template), wave-independent,
// swapped QK^T, r9-verified P swizzle (conflicts 7.3M->2.1M).
// ROUND 10: CSPLIT 4 -> 8: grid 2048 = 8 blocks/CU, launch_bounds(256,8)
// (VGPR 36 <= 64) -> 8 waves/SIMD TLP against the ~200cy/iter exposed
// serial chain (r9 counters: latency-bound at 3-4 waves/SIMD).
// ---------------------------------------------------------------------------
template <int CSPLIT>
__global__ __launch_bounds__(256, 8) void attn_kernel(const bf16_t* __restrict__ qp,
                                                      const bf16_t* __restrict__ kp,
                                                      const bf16_t* __restrict__ vpT,
                                                      bf16_t* __restrict__ Opart,
                                                      float* __restrict__ Lpart) {
    int d = blockIdx.x;
    int xcd = d & 7, j = d >> 3;
    int xb = j & 15;                  // q-tile (128 q each)
    int g = xcd + 8 * (j >> 4);       // contiguous per XCD
    int bh = g & 15, c = g >> 4;      // c in [0, CSPLIT)
    int b = bh >> 3, h = bh & 7;

    int wave = threadIdx.x >> 6, lane = threadIdx.x & 63;
    int lr = lane & 15, lg = lane >> 4;
    int q0 = xb * 128 + wave * 32;

    const bf16_t* Qb = qp + ((size_t)b * 2048 + q0) * 256 + h * 32;
    const bf16_t* Kb = kp + (size_t)b * 4096 * 256 + h * 32;
    const bf16_t* Vb = vpT + ((size_t)b * 8 + h) * 32 * 4096;

    // per-wave P tile: 32q x 32kv bf16 = 2KB, chunk-swizzled (r9)
    __shared__ __align__(16) char P_lds[4][2048];
    char* Pw = &P_lds[wave][0];

    bf16x8 qf[2];
    qf[0] = *(const bf16x8*)(Qb + (size_t)lr * 256 + lg * 8);
    qf[1] = *(const bf16x8*)(Qb + (size_t)(16 + lr) * 256 + lg * 8);

    f32x4 oacc[2][2] = {};
    float lsum[2] = {0.f, 0.f};
    const f32x4 zf = {0.f, 0.f, 0.f, 0.f};

    // P write/read byte offsets, swz = lr&6 (even -> b128 reads contiguous)
    int swz = lr & 6;
    int wb[2][2], rb[2];
#pragma unroll
    for (int ms = 0; ms < 2; ms++) {
        rb[ms] = (ms * 16 + lr) * 64 + (((lg * 2) ^ swz) << 3);
#pragma unroll
        for (int kvs = 0; kvs < 2; kvs++)
            wb[ms][kvs] = (ms * 16 + lr) * 64 + (((kvs * 4 + lg) ^ swz) << 3);
    }

    const int KVCHUNK = 4096 / CSPLIT;
    int kv_lo = c * KVCHUNK;
    for (int t = 0; t < KVCHUNK / 32; t++) {
        int kv0 = kv_lo + t * 32;
        bf16x8 kf0 = *(const bf16x8*)(Kb + (size_t)(kv0 + lr) * 256 + lg * 8);
        bf16x8 kf1 = *(const bf16x8*)(Kb + (size_t)(kv0 + 16 + lr) * 256 + lg * 8);
        bf16x8 vf0 = *(const bf16x8*)(Vb + (size_t)lr * 4096 + kv0 + lg * 8);
        bf16x8 vf1 = *(const bf16x8*)(Vb + (size_t)(16 + lr) * 4096 + kv0 + lg * 8);

        __builtin_amdgcn_s_setprio(1);
#pragma unroll
        for (int ms = 0; ms < 2; ms++) {
            // swapped: A=K rows=kv, B=Q cols=q -> lane holds (q=ms*16+lr, kv=kvs*16+lg*4+r)
            f32x4 s0 = __builtin_amdgcn_mfma_f32_16x16x32_bf16(kf0, qf[ms], zf, 0, 0, 0);
            f32x4 s1 = __builtin_amdgcn_mfma_f32_16x16x32_bf16(kf1, qf[ms], zf, 0, 0, 0);
            __builtin_amdgcn_s_setprio(0);
            float p00 = __expf(s0[0]), p01 = __expf(s0[1]);
            float p02 = __expf(s0[2]), p03 = __expf(s0[3]);
            float p10 = __expf(s1[0]), p11 = __expf(s1[1]);
            float p12 = __expf(s1[2]), p13 = __expf(s1[3]);
            lsum[ms] += (p00 + p01) + (p02 + p03) + (p10 + p11) + (p12 + p13);
            uint2 w0, w1;
            w0.x = pk2(p00, p01); w0.y = pk2(p02, p03);
            w1.x = pk2(p10, p11); w1.y = pk2(p12, p13);
            *(uint2*)(Pw + wb[ms][0]) = w0;
            *(uint2*)(Pw + wb[ms][1]) = w1;
            __builtin_amdgcn_s_setprio(1);
        }

#pragma unroll
        for (int ms = 0; ms < 2; ms++) {
            bf16x8 pf = *(const bf16x8*)(Pw + rb[ms]);
            oacc[ms][0] = __builtin_amdgcn_mfma_f32_16x16x32_bf16(pf, vf0, oacc[ms][0], 0, 0, 0);
            oacc[ms][1] = __builtin_amdgcn_mfma_f32_16x16x32_bf16(pf, vf1, oacc[ms][1], 0, 0, 0);
        }
        __builtin_amdgcn_s_setprio(0);
    }

    // lsum: partial over this lane's 8 kv slots; reduce over lg groups
#pragma unroll
    for (int ms = 0; ms < 2; ms++) {
        float s = lsum[ms];
        s += __shfl_xor(s, 16);
        s += __shfl_xor(s, 32);
        lsum[ms] = s;  // full row-sum for q = q0 + ms*16 + lr
    }

    if (lg == 0) {
        Lpart[(((size_t)c * 2 + b) * 8 + h) * 2048 + q0 + lr] = lsum[0];
        Lpart[(((size_t)c * 2 + b) * 8 + h) * 2048 + q0 + 16 + lr] = lsum[1];
    }

#pragma unroll
    for (int ms = 0; ms < 2; ms++)
#pragma unroll
        for (int r = 0; r < 4; r++) {
            int qq = q0 + ms * 16 + lg * 4 + r;
#pragma unroll
            for (int ds = 0; ds < 2; ds++) {
                int dd = h * 32 + ds * 16 + lr;
                Opart[(((size_t)c * 2 + b) * 2048 + qq) * 256 + dd] = (bf16_t)oacc[ms][ds][r];
            }
        }
}

// ---------------------------------------------------------------------------
// Kernel 4b: combine kv-split partials: o = (sum_c O_c) / (sum_c l_c).
// ---------------------------------------------------------------------------
template <int CSPLIT>
__global__ __launch_bounds__(256) void attn_combine(const bf16_t* __restrict__ Opart,
                                                    const float* __restrict__ Lpart,
                                                    bf16_t* __restrict__ o_buf) {
    int t = blockIdx.x * 256 + threadIdx.x;  // 0..131071
    int row = t >> 5;            // 0..4095  (b*2048+q)
    int c8 = (t & 31) * 8;       // col start, all 8 cols share one head
    int b = row >> 11, q = row & 2047, h = c8 >> 5;

    float acc[8] = {};
    float l = 0.f;
#pragma unroll
    for (int c = 0; c < CSPLIT; c++) {
        bf16x8 v = *(const bf16x8*)(Opart + (((size_t)c * 2 + b) * 2048 + q) * 256 + c8);
#pragma unroll
        for (int j = 0; j < 8; j++) acc[j] += (float)v[j];
        l += Lpart[(((size_t)c * 2 + b) * 8 + h) * 2048 + q];
    }
    float rl = 1.0f / l;
    bf16x8 o;
#pragma unroll
    for (int j = 0; j < 8; j++) o[j] = (bf16_t)(acc[j] * rl);
    *(bf16x8*)(o_buf + (size_t)row * 256 + c8) = o;
}

// ---------------------------------------------------------------------------
// Kernel 5: out = o @ out_w^T + out_b + points @ spatial_w^T + spatial_b
// ---------------------------------------------------------------------------
__global__ __launch_bounds__(256) void outproj_kernel(const bf16_t* __restrict__ o_buf,
                                                      const bf16_t* __restrict__ w_out,
                                                      const float* __restrict__ b_out,
                                                      const float* __restrict__ cur_pts,
                                                      const float* __restrict__ sw,
                                                      const float* __restrict__ sb,
                                                      float* __restrict__ out) {
    int wave = threadIdx.x >> 6, lane = threadIdx.x & 63;
    int wr = wave >> 1, wc = wave & 1;
    int m0 = blockIdx.y * 64 + wr * 32;
    int n0 = blockIdx.x * 64 + wc * 32;
    int lr = lane & 15, lg = lane >> 4;

    f32x4 acc[2][2] = {};
    for (int kc = 0; kc < 256; kc += 32) {
        bf16x8 a[2], b[2];
#pragma unroll
        for (int i = 0; i < 2; i++)
            a[i] = *(const bf16x8*)(o_buf + (size_t)(m0 + i * 16 + lr) * 256 + kc + lg * 8);
#pragma unroll
        for (int i = 0; i < 2; i++)
            b[i] = *(const bf16x8*)(w_out + (size_t)(n0 + i * 16 + lr) * 256 + kc + lg * 8);
#pragma unroll
        for (int i = 0; i < 2; i++)
#pragma unroll
            for (int j = 0; j < 2; j++)
                acc[i][j] = __builtin_amdgcn_mfma_f32_16x16x32_bf16(a[i], b[j], acc[i][j], 0, 0, 0);
    }

#pragma unroll
    for (int i = 0; i < 2; i++)
#pragma unroll
        for (int j = 0; j < 2; j++)
#pragma unroll
            for (int r = 0; r < 4; r++) {
                int mm = m0 + i * 16 + lg * 4 + r;
                int nn = n0 + j * 16 + lr;
                const float* pp = cur_pts + (size_t)mm * 3;
                float sp = pp[0] * sw[nn * 3 + 0] + pp[1] * sw[nn * 3 + 1] + pp[2] * sw[nn * 3 + 2] + sb[nn];
                out[(size_t)mm * 256 + nn] = acc[i][j][r] + b_out[nn] + sp;
            }
}

// ---------------------------------------------------------------------------
extern "C" void kernel_launch(void* const* d_in, const int* in_sizes, int n_in,
                              void* d_out, int out_size, void* d_ws, size_t ws_size,
                              hipStream_t stream) {
    const float* cur_pts  = (const float*)d_in[0];
    const float* cur_feat = (const float*)d_in[1];
    const float* nbr_pts  = (const float*)d_in[2];
    const float* nbr_feat = (const float*)d_in[3];
    const float* in_w     = (const float*)d_in[4];
    const float* in_b     = (const float*)d_in[5];
    const float* out_w    = (const float*)d_in[6];
    const float* out_b    = (const float*)d_in[7];
    const float* sw       = (const float*)d_in[8];
    const float* sb       = (const float*)d_in[9];

    char* ws = (char*)d_ws;
    bf16_t* w_in_b  = (bf16_t*)(ws + 0);          //  768*256*2 = 393216
    bf16_t* w_out_b = (bf16_t*)(ws + 393216);     //  256*256*2 = 131072
    int*    idx_buf = (int*)(ws + 524288);        //  6*2048*8*4 = 393216
    bf16_t* cur_edge = (bf16_t*)(ws + 917504);    //  4096*256*2 = 2097152
    bf16_t* all_nbr  = (bf16_t*)(ws + 3014656);   //  8192*256*2 = 4194304
    bf16_t* qp  = (bf16_t*)(ws + 7208960);        //  4096*256*2
    bf16_t* kp  = (bf16_t*)(ws + 9306112);        //  8192*256*2
    bf16_t* vpT = (bf16_t*)(ws + 13500416);       //  2*8*32*4096*2
    bf16_t* o_buf = (bf16_t*)(ws + 17694720);     //  4096*256*2 = 2097152
    bf16_t* Opart = (bf16_t*)(ws + 19791872);     //  c=8: 8*2*2048*256*2 = 16777216
    // vp (row-major V projection, 4MB) aliases Opart: fully consumed by
    // vt_kernel before attn_kernel writes Opart.
    bf16_t* vp = (bf16_t*)(ws + 19791872);
    float* outp = (float*)d_out;

    wconv_kernel<<<dim3(768), dim3(256), 0, stream>>>(in_w, out_w, w_in_b, w_out_b);
    knn_kernel<<<dim3(128, 6), dim3(1024), 0, stream>>>(cur_pts, nbr_pts, idx_buf);
    edge_kernel<<<dim3(12288), dim3(64), 0, stream>>>(cur_feat, nbr_feat, idx_buf, cur_edge, all_nbr);
    qkv_kernel<<<dim3(4, 128, 3), dim3(256), 0, stream>>>(cur_edge, all_nbr, w_in_b, in_b, qp, kp, vp);
    vt_kernel<<<dim3(64, 16), dim3(256), 0, stream>>>(vp, vpT);

    // c=8 needs Opart(16.8MB)+Lpart(1MB) ending at ~37.6MB; guard on ws_size
    // (deterministic per deployment -> graph-safe).
    if (ws_size >= (size_t)19791872 + 16777216 + 1048576) {
        float* Lpart = (float*)(ws + 19791872 + 16777216);
        attn_kernel<8><<<dim3(2048), dim3(256), 0, stream>>>(qp, kp, vpT, Opart, Lpart);
        attn_combine<8><<<dim3(512), dim3(256), 0, stream>>>(Opart, Lpart, o_buf);
    } else {
        float* Lpart = (float*)(ws + 28180480);
        attn_kernel<4><<<dim3(1024), dim3(256), 0, stream>>>(qp, kp, vpT, Opart, Lpart);
        attn_combine<4><<<dim3(512), dim3(256), 0, stream>>>(Opart, Lpart, o_buf);
    }
    outproj_kernel<<<dim3(4, 64), dim3(256), 0, stream>>>(o_buf, w_out_b, out_b, cur_pts, sw, sb, outp);
}

// Round 12
// 201.494 us; speedup vs baseline: 1.1208x; 1.1208x over previous
//
#include <hip/hip_runtime.h>
#include <hip/hip_bf16.h>

typedef __bf16 bf16_t;
typedef __attribute__((ext_vector_type(8))) __bf16 bf16x8;
typedef __attribute__((ext_vector_type(4))) __bf16 bf16x4;
typedef __attribute__((ext_vector_type(4))) float f32x4;

// Problem constants
// B=2, N=2048, D=256, H=8, M=2, NN=2048, K=8, dh=32

// ---------------------------------------------------------------------------
// Kernel 0: convert weights to bf16
// ---------------------------------------------------------------------------
__global__ __launch_bounds__(256) void wconv_kernel(const float* __restrict__ w_in,
                                                    const float* __restrict__ w_out,
                                                    bf16_t* __restrict__ w_in_b,
                                                    bf16_t* __restrict__ w_out_b) {
    int i = blockIdx.x * 256 + threadIdx.x;
    if (i < 768 * 256) w_in_b[i] = (bf16_t)w_in[i];
    if (i < 256 * 256) w_out_b[i] = (bf16_t)w_out[i];
}

// ---------------------------------------------------------------------------
// Kernel 1: KNN top-8, one WAVE per query. (unchanged, proven)
// ---------------------------------------------------------------------------
__global__ __launch_bounds__(1024) void knn_kernel(const float* __restrict__ cur_pts,
                                                   const float* __restrict__ nbr_pts,
                                                   int* __restrict__ idx_out) {
    int p = blockIdx.y;  // 0..5 : 0,1 = current batches; 2..5 = (m*2+b)
    const float* pts = (p < 2) ? (cur_pts + (size_t)p * 2048 * 3)
                               : (nbr_pts + (size_t)(p - 2) * 2048 * 3);

    __shared__ __align__(16) float4 spts[2048];

    int tid = threadIdx.x;
    for (int i = tid; i < 2048; i += 1024) {
        float x = pts[i * 3 + 0], y = pts[i * 3 + 1], z = pts[i * 3 + 2];
        float sq = __fadd_rn(__fadd_rn(__fmul_rn(x, x), __fmul_rn(y, y)), __fmul_rn(z, z));
        spts[i] = make_float4(x, y, z, sq);
    }
    __syncthreads();

    int wave = tid >> 6, lane = tid & 63;
    int q = blockIdx.x * 16 + wave;
    float4 qp4 = spts[q];

    float dist[8];
    int di[8];
#pragma unroll
    for (int r = 0; r < 8; r++) { dist[r] = 3.4e38f; di[r] = 0x7fffffff; }

    for (int t = 0; t < 32; t++) {
        int j = t * 64 + lane;
        float4 pp = spts[j];
        float dot = __fadd_rn(__fadd_rn(__fmul_rn(qp4.x, pp.x), __fmul_rn(qp4.y, pp.y)),
                              __fmul_rn(qp4.z, pp.z));
        float d2 = __fsub_rn(__fadd_rn(qp4.w, pp.w), __fmul_rn(2.0f, dot));
        if (d2 < dist[7]) {
#pragma unroll
            for (int r = 7; r >= 1; --r) {
                bool cm = d2 < dist[r - 1];
                bool cr = d2 < dist[r];
                float nd = cm ? dist[r - 1] : (cr ? d2 : dist[r]);
                int ni = cm ? di[r - 1] : (cr ? j : di[r]);
                dist[r] = nd; di[r] = ni;
            }
            if (d2 < dist[0]) { dist[0] = d2; di[0] = j; }
        }
    }

    int res[8];
#pragma unroll
    for (int r = 0; r < 8; r++) {
        float bd = dist[0];
        int bi = di[0];
#pragma unroll
        for (int m = 1; m < 64; m <<= 1) {
            float od = __shfl_xor(bd, m);
            int oi = __shfl_xor(bi, m);
            if (od < bd || (od == bd && oi < bi)) { bd = od; bi = oi; }
        }
        res[r] = bi;
        bool win = (di[0] == bi);
#pragma unroll
        for (int k = 0; k < 7; k++) {
            dist[k] = win ? dist[k + 1] : dist[k];
            di[k]   = win ? di[k + 1]   : di[k];
        }
        if (win) { dist[7] = 3.4e38f; di[7] = 0x7fffffff; }
    }

    if (lane == 0) {
        int4* o = (int4*)(idx_out + ((size_t)p * 2048 + q) * 8);
        o[0] = make_int4(res[0], res[1], res[2], res[3]);
        o[1] = make_int4(res[4], res[5], res[6], res[7]);
    }
}

// ---------------------------------------------------------------------------
// Kernel 2: gather neighbor features, edge = f - mean(nbr). (unchanged)
// ---------------------------------------------------------------------------
__global__ __launch_bounds__(64) void edge_kernel(const float* __restrict__ cur_feat,
                                                  const float* __restrict__ nbr_feat,
                                                  const int* __restrict__ idx_buf,
                                                  bf16_t* __restrict__ cur_edge,
                                                  bf16_t* __restrict__ all_nbr) {
    int blk = blockIdx.x;
    int p = blk >> 11, q = blk & 2047;
    const float* feat;
    bf16_t* outp;
    if (p < 2) {
        feat = cur_feat + (size_t)p * 2048 * 256;
        outp = cur_edge + ((size_t)p * 2048 + q) * 256;
    } else {
        int mb = p - 2;
        int m = mb >> 1, bb = mb & 1;
        feat = nbr_feat + (size_t)mb * 2048 * 256;
        outp = all_nbr + ((size_t)bb * 4096 + m * 2048 + q) * 256;
    }
    const int* idx = idx_buf + ((size_t)p * 2048 + q) * 8;
    int t = threadIdx.x;
    float4 self = ((const float4*)(feat + (size_t)q * 256))[t];
    float sx = 0.f, sy = 0.f, sz = 0.f, sw = 0.f;
#pragma unroll
    for (int r = 0; r < 8; r++) {
        float4 f = ((const float4*)(feat + (size_t)idx[r] * 256))[t];
        sx += f.x; sy += f.y; sz += f.z; sw += f.w;
    }
    bf16x4 v;
    v[0] = (bf16_t)(self.x - sx * 0.125f);
    v[1] = (bf16_t)(self.y - sy * 0.125f);
    v[2] = (bf16_t)(self.z - sz * 0.125f);
    v[3] = (bf16_t)(self.w - sw * 0.125f);
    *(bf16x4*)(outp + 4 * t) = v;
}

// ---------------------------------------------------------------------------
// Kernel 3: QKV projections via bf16 MFMA. z=0: qp (scaled), z=1: kp,
// z=2: vp ROW-major (coalesced); vt_kernel transposes after.
// ---------------------------------------------------------------------------
__global__ __launch_bounds__(256) void qkv_kernel(const bf16_t* __restrict__ cur_edge,
                                                  const bf16_t* __restrict__ all_nbr,
                                                  const bf16_t* __restrict__ w_in,
                                                  const float* __restrict__ b_in,
                                                  bf16_t* __restrict__ qp,
                                                  bf16_t* __restrict__ kp,
                                                  bf16_t* __restrict__ vp) {
    int z = blockIdx.z;
    int Mrows = (z == 0) ? 4096 : 8192;
    int m0base = blockIdx.y * 64;
    if (m0base >= Mrows) return;
    const bf16_t* A = (z == 0) ? cur_edge : all_nbr;
    const bf16_t* W = w_in + (size_t)z * 256 * 256;

    int wave = threadIdx.x >> 6, lane = threadIdx.x & 63;
    int wr = wave >> 1, wc = wave & 1;
    int m0 = m0base + wr * 32;
    int n0 = blockIdx.x * 64 + wc * 32;
    int lr = lane & 15, lg = lane >> 4;

    f32x4 acc[2][2] = {};
    for (int kc = 0; kc < 256; kc += 32) {
        bf16x8 a[2], b[2];
#pragma unroll
        for (int i = 0; i < 2; i++)
            a[i] = *(const bf16x8*)(A + (size_t)(m0 + i * 16 + lr) * 256 + kc + lg * 8);
#pragma unroll
        for (int i = 0; i < 2; i++)
            b[i] = *(const bf16x8*)(W + (size_t)(n0 + i * 16 + lr) * 256 + kc + lg * 8);
#pragma unroll
        for (int i = 0; i < 2; i++)
#pragma unroll
            for (int j = 0; j < 2; j++)
                acc[i][j] = __builtin_amdgcn_mfma_f32_16x16x32_bf16(a[i], b[j], acc[i][j], 0, 0, 0);
    }

    const float inv_s = 0.17677669529663687f;  // 1/sqrt(32)
#pragma unroll
    for (int i = 0; i < 2; i++)
#pragma unroll
        for (int j = 0; j < 2; j++)
#pragma unroll
            for (int r = 0; r < 4; r++) {
                int mm = m0 + i * 16 + lg * 4 + r;
                int nn = n0 + j * 16 + lr;
                float v = acc[i][j][r] + b_in[z * 256 + nn];
                if (z == 0) {
                    qp[(size_t)mm * 256 + nn] = (bf16_t)(v * inv_s);
                } else if (z == 1) {
                    kp[(size_t)mm * 256 + nn] = (bf16_t)v;
                } else {
                    vp[(size_t)mm * 256 + nn] = (bf16_t)v;
                }
            }
}

// ---------------------------------------------------------------------------
// Kernel 3b: transpose vp -> vpT [b,h,32dd][4096kv] via padded LDS tile.
// ---------------------------------------------------------------------------
__global__ __launch_bounds__(256) void vt_kernel(const bf16_t* __restrict__ vp,
                                                 bf16_t* __restrict__ vpT) {
    int kc = blockIdx.x;          // kv chunk of 64 (0..63)
    int bh = blockIdx.y;          // 0..15
    int b = bh >> 3, h = bh & 7;
    __shared__ bf16_t tile[64][34];
    int tid = threadIdx.x;

    const bf16_t* src = vp + ((size_t)b * 4096 + kc * 64) * 256 + h * 32;
    int dd0 = (tid & 7) * 4, kvr = tid >> 3;          // 32 kv rows per pass
#pragma unroll
    for (int it = 0; it < 2; it++) {
        int kv = it * 32 + kvr;
        bf16x4 v = *(const bf16x4*)(src + (size_t)kv * 256 + dd0);
#pragma unroll
        for (int j = 0; j < 4; j++) tile[kv][dd0 + j] = v[j];
    }
    __syncthreads();

    bf16_t* dst = vpT + (((size_t)b * 8 + h) * 32) * 4096 + kc * 64;
    int kv0 = (tid & 15) * 4, ddr0 = tid >> 4;        // 16 dd rows per pass
#pragma unroll
    for (int it = 0; it < 2; it++) {
        int dd = it * 16 + ddr0;
        bf16x4 v;
#pragma unroll
        for (int j = 0; j < 4; j++) v[j] = tile[kv0 + j][dd];
        *(bf16x4*)(dst + (size_t)dd * 4096 + kv0) = v;
    }
}

// ---------------------------------------------------------------------------
// Kernel 4: cross attention — ROUND-6 STRUCTURE RESTORED (best measured:
// 48.4us). kv-SPLIT (c=4) partial softmax + block-cooperative LDS staging:
//   - wave owns 16 q rows; block = 4 waves = 64 q rows; grid (32,16,4) =
//     2048 blocks = 8 blocks/CU.
//   - per 32-kv tile: 256 threads cooperatively stage K-slice + V-slice
//     into a 4KB fragment-major LDS tile (addr = tid*16): staging writes
//     and frag reads linear; ONE global load of each K/V byte per block
//     (the r8-r10 direct-global variants quadrupled per-CU load issue and
//     saturated the vector-memory path: TLP-independent 70us plateau).
//   - next tile's global load issued before the barrier (partial overlap).
//   - P round-trips per-wave LDS in fragment-major order.
// ---------------------------------------------------------------------------
__global__ __launch_bounds__(256, 8) void attn_kernel(const bf16_t* __restrict__ qp,
                                                      const bf16_t* __restrict__ kp,
                                                      const bf16_t* __restrict__ vpT,
                                                      bf16_t* __restrict__ Opart,
                                                      float* __restrict__ Lpart) {
    int bh = blockIdx.y;
    int b = bh >> 3, h = bh & 7;
    int c = blockIdx.z;  // kv chunk 0..3
    int wave = threadIdx.x >> 6, lane = threadIdx.x & 63;
    int lr = lane & 15, lg = lane >> 4;
    int q0 = blockIdx.x * 64 + wave * 16;

    const bf16_t* Qb = qp + ((size_t)b * 2048 + q0) * 256 + h * 32;
    const bf16_t* Kb = kp + (size_t)b * 4096 * 256 + h * 32;
    const bf16_t* Vb = vpT + ((size_t)b * 8 + h) * 32 * 4096;

    // fragment-major staged K/V tile: elems [0,512)=kf0, [512,1024)=kf1,
    // [1024,1536)=vf0, [1536,2048)=vf1 ; each chunk = 64 lanes x 8 bf16
    __shared__ __align__(16) bf16_t KV[2048];
    // per-wave fragment-major P (16 q x 32 kv): read addr = lane*16, linear
    __shared__ __align__(16) bf16_t P_lds[4][512];
    bf16_t* Pw = &P_lds[wave][0];

    bf16x8 qfrag = *(const bf16x8*)(Qb + (size_t)lr * 256 + lg * 8);

    f32x4 oacc[2] = {};
    float lsum[4] = {};
    const f32x4 zf = {0.f, 0.f, 0.f, 0.f};

    int kv_lo = c * 1024;

    // staging role: wave 0 -> K rows 0..15, wave 1 -> K rows 16..31,
    // wave 2 -> V rows 0..15, wave 3 -> V rows 16..31 (rows per tile)
    int role = wave;
    int tlr = lr, tlg = lg;
    const bf16_t* gsrc;
    size_t gstep;
    if (role < 2) {
        gsrc = Kb + (size_t)(kv_lo + role * 16 + tlr) * 256 + tlg * 8;
        gstep = 32 * 256;
    } else {
        gsrc = Vb + (size_t)((role - 2) * 16 + tlr) * 4096 + kv_lo + tlg * 8;
        gstep = 32;
    }
    bf16_t* stage_dst = &KV[(size_t)threadIdx.x * 8];

    bf16x8 g = *(const bf16x8*)gsrc;
    gsrc += gstep;

    for (int t = 0; t < 32; t++) {
        *(bf16x8*)stage_dst = g;                       // ds_write_b128 (linear)
        if (t + 1 < 32) {                              // issue next load early
            g = *(const bf16x8*)gsrc;
            gsrc += gstep;
        }
        __syncthreads();                               // staged tile visible

        bf16x8 kf0 = *(const bf16x8*)(KV + (size_t)lane * 8);
        bf16x8 kf1 = *(const bf16x8*)(KV + 512 + (size_t)lane * 8);
        bf16x8 vf0 = *(const bf16x8*)(KV + 1024 + (size_t)lane * 8);
        bf16x8 vf1 = *(const bf16x8*)(KV + 1536 + (size_t)lane * 8);

        f32x4 s0 = __builtin_amdgcn_mfma_f32_16x16x32_bf16(qfrag, kf0, zf, 0, 0, 0);
        f32x4 s1 = __builtin_amdgcn_mfma_f32_16x16x32_bf16(qfrag, kf1, zf, 0, 0, 0);
#pragma unroll
        for (int r = 0; r < 4; r++) {
            float p0 = __expf(s0[r]);
            float p1 = __expf(s1[r]);
            lsum[r] += p0 + p1;
            // fragment-major: addr(q,kv) = (kv>>3)*128 + q*8 + (kv&7)
            Pw[((lr >> 3) * 128) + (lg * 4 + r) * 8 + (lr & 7)] = (bf16_t)p0;       // kv=lr
            Pw[((2 + (lr >> 3)) * 128) + (lg * 4 + r) * 8 + (lr & 7)] = (bf16_t)p1; // kv=16+lr
        }
        bf16x8 pf = *(const bf16x8*)(Pw + (size_t)lane * 8);
        oacc[0] = __builtin_amdgcn_mfma_f32_16x16x32_bf16(pf, vf0, oacc[0], 0, 0, 0);
        oacc[1] = __builtin_amdgcn_mfma_f32_16x16x32_bf16(pf, vf1, oacc[1], 0, 0, 0);

        __syncthreads();                               // all reads done before re-stage
    }

    // row sums: reduce across the 16 lanes (lr) sharing each lg group
#pragma unroll
    for (int r = 0; r < 4; r++) {
        float s = lsum[r];
        s += __shfl_xor(s, 1);
        s += __shfl_xor(s, 2);
        s += __shfl_xor(s, 4);
        s += __shfl_xor(s, 8);
        lsum[r] = s;
    }

    // partial writes: unnormalized O (bf16) and row-sum l (f32, lane lr==0)
#pragma unroll
    for (int r = 0; r < 4; r++) {
        int qq = q0 + lg * 4 + r;
        if (lr == 0)
            Lpart[(((size_t)c * 2 + b) * 8 + h) * 2048 + qq] = lsum[r];
#pragma unroll
        for (int ds = 0; ds < 2; ds++) {
            int dd = h * 32 + ds * 16 + lr;
            Opart[(((size_t)c * 2 + b) * 2048 + qq) * 256 + dd] = (bf16_t)oacc[ds][r];
        }
    }
}

// ---------------------------------------------------------------------------
// Kernel 4b: combine kv-split partials: o = (sum_c O_c) / (sum_c l_c).
// ---------------------------------------------------------------------------
__global__ __launch_bounds__(256) void attn_combine(const bf16_t* __restrict__ Opart,
                                                    const float* __restrict__ Lpart,
                                                    bf16_t* __restrict__ o_buf) {
    int t = blockIdx.x * 256 + threadIdx.x;  // 0..131071
    int row = t >> 5;            // 0..4095  (b*2048+q)
    int c8 = (t & 31) * 8;       // col start, all 8 cols share one head
    int b = row >> 11, q = row & 2047, h = c8 >> 5;

    float acc[8] = {};
    float l = 0.f;
#pragma unroll
    for (int c = 0; c < 4; c++) {
        bf16x8 v = *(const bf16x8*)(Opart + (((size_t)c * 2 + b) * 2048 + q) * 256 + c8);
#pragma unroll
        for (int j = 0; j < 8; j++) acc[j] += (float)v[j];
        l += Lpart[(((size_t)c * 2 + b) * 8 + h) * 2048 + q];
    }
    float rl = 1.0f / l;
    bf16x8 o;
#pragma unroll
    for (int j = 0; j < 8; j++) o[j] = (bf16_t)(acc[j] * rl);
    *(bf16x8*)(o_buf + (size_t)row * 256 + c8) = o;
}

// ---------------------------------------------------------------------------
// Kernel 5: out = o @ out_w^T + out_b + points @ spatial_w^T + spatial_b
// ---------------------------------------------------------------------------
__global__ __launch_bounds__(256) void outproj_kernel(const bf16_t* __restrict__ o_buf,
                                                      const bf16_t* __restrict__ w_out,
                                                      const float* __restrict__ b_out,
                                                      const float* __restrict__ cur_pts,
                                                      const float* __restrict__ sw,
                                                      const float* __restrict__ sb,
                                                      float* __restrict__ out) {
    int wave = threadIdx.x >> 6, lane = threadIdx.x & 63;
    int wr = wave >> 1, wc = wave & 1;
    int m0 = blockIdx.y * 64 + wr * 32;
    int n0 = blockIdx.x * 64 + wc * 32;
    int lr = lane & 15, lg = lane >> 4;

    f32x4 acc[2][2] = {};
    for (int kc = 0; kc < 256; kc += 32) {
        bf16x8 a[2], b[2];
#pragma unroll
        for (int i = 0; i < 2; i++)
            a[i] = *(const bf16x8*)(o_buf + (size_t)(m0 + i * 16 + lr) * 256 + kc + lg * 8);
#pragma unroll
        for (int i = 0; i < 2; i++)
            b[i] = *(const bf16x8*)(w_out + (size_t)(n0 + i * 16 + lr) * 256 + kc + lg * 8);
#pragma unroll
        for (int i = 0; i < 2; i++)
#pragma unroll
            for (int j = 0; j < 2; j++)
                acc[i][j] = __builtin_amdgcn_mfma_f32_16x16x32_bf16(a[i], b[j], acc[i][j], 0, 0, 0);
    }

#pragma unroll
    for (int i = 0; i < 2; i++)
#pragma unroll
        for (int j = 0; j < 2; j++)
#pragma unroll
            for (int r = 0; r < 4; r++) {
                int mm = m0 + i * 16 + lg * 4 + r;
                int nn = n0 + j * 16 + lr;
                const float* pp = cur_pts + (size_t)mm * 3;
                float sp = pp[0] * sw[nn * 3 + 0] + pp[1] * sw[nn * 3 + 1] + pp[2] * sw[nn * 3 + 2] + sb[nn];
                out[(size_t)mm * 256 + nn] = acc[i][j][r] + b_out[nn] + sp;
            }
}

// ---------------------------------------------------------------------------
extern "C" void kernel_launch(void* const* d_in, const int* in_sizes, int n_in,
                              void* d_out, int out_size, void* d_ws, size_t ws_size,
                              hipStream_t stream) {
    const float* cur_pts  = (const float*)d_in[0];
    const float* cur_feat = (const float*)d_in[1];
    const float* nbr_pts  = (const float*)d_in[2];
    const float* nbr_feat = (const float*)d_in[3];
    const float* in_w     = (const float*)d_in[4];
    const float* in_b     = (const float*)d_in[5];
    const float* out_w    = (const float*)d_in[6];
    const float* out_b    = (const float*)d_in[7];
    const float* sw       = (const float*)d_in[8];
    const float* sb       = (const float*)d_in[9];

    char* ws = (char*)d_ws;
    bf16_t* w_in_b  = (bf16_t*)(ws + 0);          //  768*256*2 = 393216
    bf16_t* w_out_b = (bf16_t*)(ws + 393216);     //  256*256*2 = 131072
    int*    idx_buf = (int*)(ws + 524288);        //  6*2048*8*4 = 393216
    bf16_t* cur_edge = (bf16_t*)(ws + 917504);    //  4096*256*2 = 2097152
    bf16_t* all_nbr  = (bf16_t*)(ws + 3014656);   //  8192*256*2 = 4194304
    bf16_t* qp  = (bf16_t*)(ws + 7208960);        //  4096*256*2
    bf16_t* kp  = (bf16_t*)(ws + 9306112);        //  8192*256*2
    bf16_t* vpT = (bf16_t*)(ws + 13500416);       //  2*8*32*4096*2
    bf16_t* o_buf = (bf16_t*)(ws + 17694720);     //  4096*256*2 = 2097152
    bf16_t* Opart = (bf16_t*)(ws + 19791872);     //  4*2*2048*256*2 = 8388608
    float*  Lpart = (float*)(ws + 28180480);      //  4*2*8*2048*4 = 524288  (end 28704768)
    // vp (row-major V projection, 4MB) aliases Opart: fully consumed by
    // vt_kernel before attn_kernel writes Opart.
    bf16_t* vp = (bf16_t*)(ws + 19791872);
    float* outp = (float*)d_out;

    wconv_kernel<<<dim3(768), dim3(256), 0, stream>>>(in_w, out_w, w_in_b, w_out_b);
    knn_kernel<<<dim3(128, 6), dim3(1024), 0, stream>>>(cur_pts, nbr_pts, idx_buf);
    edge_kernel<<<dim3(12288), dim3(64), 0, stream>>>(cur_feat, nbr_feat, idx_buf, cur_edge, all_nbr);
    qkv_kernel<<<dim3(4, 128, 3), dim3(256), 0, stream>>>(cur_edge, all_nbr, w_in_b, in_b, qp, kp, vp);
    vt_kernel<<<dim3(64, 16), dim3(256), 0, stream>>>(vp, vpT);
    attn_kernel<<<dim3(32, 16, 4), dim3(256), 0, stream>>>(qp, kp, vpT, Opart, Lpart);
    attn_combine<<<dim3(512), dim3(256), 0, stream>>>(Opart, Lpart, o_buf);
    outproj_kernel<<<dim3(4, 64), dim3(256), 0, stream>>>(o_buf, w_out_b, out_b, cur_pts, sw, sb, outp);
}